// Round 1
// baseline (477.412 us; speedup 1.0000x reference)
//
#include <hip/hip_runtime.h>

// SpectralAttention: y = (softmax_causal((xWq^T)(xWk^T)^T/8) (xWv^T)) Wo^T
// B=4 T=2048 C=1024 H=16 hd=64. All GEMMs via mfma_f32_16x16x32_bf16.

#define B_ 4
#define T_ 2048
#define C_ 1024
#define H_ 16
#define M_ 8192  // B*T

typedef unsigned short u16;
typedef __bf16 bf16x8 __attribute__((ext_vector_type(8)));
typedef float f32x4 __attribute__((ext_vector_type(4)));

static __device__ __forceinline__ u16 f2bf(float f) {
  unsigned int u = __float_as_uint(f);
  u += 0x7fffu + ((u >> 16) & 1u);  // RNE; inputs finite
  return (u16)(u >> 16);
}

static __device__ __forceinline__ void async16(const void* g, void* l) {
  // global -> LDS direct copy, 16B/lane; LDS dest = wave-uniform base + lane*16
  __builtin_amdgcn_global_load_lds(
      (const __attribute__((address_space(1))) unsigned int*)g,
      (__attribute__((address_space(3))) unsigned int*)l, 16, 0, 0);
}

#if __has_builtin(__builtin_amdgcn_exp2f)
#define EXP2F(x) __builtin_amdgcn_exp2f(x)
#else
#define EXP2F(x) exp2f(x)
#endif

// ---------------- fp32 -> bf16 ----------------
__global__ __launch_bounds__(256) void cvt_bf16(const float* __restrict__ src,
                                                u16* __restrict__ dst, int n4) {
  int i = blockIdx.x * 256 + threadIdx.x;
  if (i >= n4) return;
  float4 f = ((const float4*)src)[i];
  ushort4 o;
  o.x = f2bf(f.x); o.y = f2bf(f.y); o.z = f2bf(f.z); o.w = f2bf(f.w);
  ((ushort4*)dst)[i] = o;
}

// ---------------- C[m,n] = sum_k A[m,k] Bt[n,k] + bias[n] ----------------
// A:[M,K] bf16, Bt:[N,K] bf16 (row-major). 128x128 tile, 4 waves of 64x64,
// BK=32. LDS chunk swizzle: chunk cc at row r holds global chunk cc^(r&3).
__global__ __launch_bounds__(256) void gemm_bt(const u16* __restrict__ A,
                                               const u16* __restrict__ Bt,
                                               const float* __restrict__ bias,
                                               float* __restrict__ outf,
                                               u16* __restrict__ outb,
                                               int M, int N, int K) {
  __shared__ __align__(16) u16 Asm[128 * 32];
  __shared__ __align__(16) u16 Bsm[128 * 32];
  const int tid = threadIdx.x, lane = tid & 63, wave = tid >> 6;
  const int quad = lane >> 4, l16 = lane & 15;
  const int wm = wave >> 1, wn = wave & 1;
  const int row0 = blockIdx.y * 128, col0 = blockIdx.x * 128;

  f32x4 acc[4][4];
#pragma unroll
  for (int i = 0; i < 4; i++)
#pragma unroll
    for (int j = 0; j < 4; j++) acc[i][j] = (f32x4){0.f, 0.f, 0.f, 0.f};

  for (int k0 = 0; k0 < K; k0 += 32) {
#pragma unroll
    for (int i = 0; i < 2; i++) {
      int c = wave * 128 + i * 64 + lane;  // 16B chunk id, 512 total per tile
      int r = c >> 2;
      int gcc = (c & 3) ^ (r & 3);
      async16(A + (size_t)(row0 + r) * K + k0 + gcc * 8,
              Asm + (size_t)(wave * 128 + i * 64) * 8);
      async16(Bt + (size_t)(col0 + r) * K + k0 + gcc * 8,
              Bsm + (size_t)(wave * 128 + i * 64) * 8);
    }
    __syncthreads();  // drains vmcnt (global_load_lds) before use

    bf16x8 a[4], b[4];
#pragma unroll
    for (int i = 0; i < 4; i++) {
      int rm = wm * 64 + 16 * i + l16;
      a[i] = *(const bf16x8*)(Asm + rm * 32 + (quad ^ (rm & 3)) * 8);
      int rn = wn * 64 + 16 * i + l16;
      b[i] = *(const bf16x8*)(Bsm + rn * 32 + (quad ^ (rn & 3)) * 8);
    }
#pragma unroll
    for (int i = 0; i < 4; i++)
#pragma unroll
      for (int j = 0; j < 4; j++)
        acc[i][j] =
            __builtin_amdgcn_mfma_f32_16x16x32_bf16(a[i], b[j], acc[i][j], 0, 0, 0);
    __syncthreads();
  }

  float bj[4];
#pragma unroll
  for (int j = 0; j < 4; j++) bj[j] = bias[col0 + wn * 64 + 16 * j + l16];
#pragma unroll
  for (int i = 0; i < 4; i++) {
#pragma unroll
    for (int j = 0; j < 4; j++) {
      int gcol = col0 + wn * 64 + 16 * j + l16;
#pragma unroll
      for (int r = 0; r < 4; r++) {
        // C/D layout: col = lane&15, row = quad*4 + reg  [m89-verified]
        int grow = row0 + wm * 64 + 16 * i + quad * 4 + r;
        float v = acc[i][j][r] + bj[j];
        if (outf) outf[(size_t)grow * N + gcol] = v;
        else outb[(size_t)grow * N + gcol] = f2bf(v);
      }
    }
  }
}

// ---------------- per-head V transpose: [T,64] -> [64,T] ----------------
__global__ __launch_bounds__(256) void transpose_v(const u16* __restrict__ v,
                                                   u16* __restrict__ vt) {
  __shared__ __align__(16) u16 tile[64][72];
  const int tid = threadIdx.x;
  const int t0 = blockIdx.x * 64;
  const int bh = blockIdx.y;
  const int b = bh >> 4, h = bh & 15;
#pragma unroll
  for (int i = 0; i < 2; i++) {
    int r = (tid >> 3) + i * 32;
    int c8 = (tid & 7) * 8;
    *(uint4*)(&tile[r][c8]) =
        *(const uint4*)(v + (size_t)(b * T_ + t0 + r) * C_ + h * 64 + c8);
  }
  __syncthreads();
#pragma unroll
  for (int i = 0; i < 2; i++) {
    int d = (tid >> 3) + i * 32;
    int t8 = (tid & 7) * 8;
    __align__(16) u16 tmp[8];
#pragma unroll
    for (int e = 0; e < 8; e++) tmp[e] = tile[t8 + e][d];
    *(uint4*)(vt + (size_t)(bh * 64 + d) * T_ + t0 + t8) = *(const uint4*)tmp;
  }
}

// ---------------- flash attention (causal) ----------------
// block = (qt, b*H+h): 64 Q-rows; 4 waves x 16 rows. K tile [64kv][64d],
// V^T tile [64d][64kv] in LDS (8-chunk rows, swizzle cc^(r&7) -> <=2-way).
__global__ __launch_bounds__(256) void attn(const u16* __restrict__ q,
                                            const u16* __restrict__ k,
                                            const u16* __restrict__ vt,
                                            u16* __restrict__ y) {
  __shared__ __align__(16) u16 Ksm[64 * 64];
  __shared__ __align__(16) u16 Vsm[64 * 64];
  __shared__ __align__(16) u16 Psm[4][16 * 64];
  const int tid = threadIdx.x, lane = tid & 63, wave = tid >> 6;
  const int quad = lane >> 4, l16 = lane & 15;
  const int qt = blockIdx.x, bh = blockIdx.y;
  const int b = bh >> 4, h = bh & 15;
  const float LOG2E = 1.4426950408889634f;

  // Q fragments (A-operand: m=lane&15, k=quad*8+j), held for whole block
  bf16x8 qf[2];
  {
    const u16* qp = q + (size_t)(b * T_ + qt * 64 + wave * 16 + l16) * C_ + h * 64;
    qf[0] = *(const bf16x8*)(qp + quad * 8);
    qf[1] = *(const bf16x8*)(qp + 32 + quad * 8);
  }
  float m_r[4], l_r[4];
  f32x4 o[4];
#pragma unroll
  for (int r = 0; r < 4; r++) { m_r[r] = -1e30f; l_r[r] = 0.f; }
#pragma unroll
  for (int dt = 0; dt < 4; dt++) o[dt] = (f32x4){0.f, 0.f, 0.f, 0.f};

  for (int t = 0; t <= qt; ++t) {
    const int j0 = t * 64;
#pragma unroll
    for (int i = 0; i < 2; i++) {
      int c = wave * 128 + i * 64 + lane;  // 512 chunks of 16B per tile
      int r = c >> 3;
      int gcc = (c & 7) ^ (r & 7);
      async16(k + (size_t)(b * T_ + j0 + r) * C_ + h * 64 + gcc * 8,
              Ksm + (size_t)(wave * 128 + i * 64) * 8);
      async16(vt + (size_t)(bh * 64 + r) * T_ + j0 + gcc * 8,
              Vsm + (size_t)(wave * 128 + i * 64) * 8);
    }
    __syncthreads();

    // S = Q K^T  (B-operand n = kv = lane&15 -> K row; k = d contiguous)
    f32x4 S[4];
#pragma unroll
    for (int n = 0; n < 4; n++) {
      f32x4 s = (f32x4){0.f, 0.f, 0.f, 0.f};
      int rk = n * 16 + l16;
#pragma unroll
      for (int ks = 0; ks < 2; ks++) {
        bf16x8 kf =
            *(const bf16x8*)(Ksm + rk * 64 + (((ks * 4 + quad) ^ (rk & 7)) * 8));
        s = __builtin_amdgcn_mfma_f32_16x16x32_bf16(qf[ks], kf, s, 0, 0, 0);
      }
      S[n] = s;
    }

    const bool diag = (t == qt);
#pragma unroll
    for (int n = 0; n < 4; n++) {
      int kv = j0 + n * 16 + l16;
#pragma unroll
      for (int r = 0; r < 4; r++) {
        float sv = S[n][r] * 0.125f;  // hd^-0.5
        int qa = qt * 64 + wave * 16 + quad * 4 + r;
        if (diag && kv > qa) sv = -1e30f;
        S[n][r] = sv;
      }
    }

    // online softmax; row (quad,reg) spread over 16 lanes of the quad
    float alpha[4];
#pragma unroll
    for (int r = 0; r < 4; r++) {
      float mx = fmaxf(fmaxf(S[0][r], S[1][r]), fmaxf(S[2][r], S[3][r]));
      mx = fmaxf(mx, __shfl_xor(mx, 1));
      mx = fmaxf(mx, __shfl_xor(mx, 2));
      mx = fmaxf(mx, __shfl_xor(mx, 4));
      mx = fmaxf(mx, __shfl_xor(mx, 8));
      float mnew = fmaxf(m_r[r], mx);
      alpha[r] = EXP2F((m_r[r] - mnew) * LOG2E);
      m_r[r] = mnew;
      float sum = 0.f;
#pragma unroll
      for (int n = 0; n < 4; n++) {
        float p = EXP2F((S[n][r] - mnew) * LOG2E);
        S[n][r] = p;
        sum += p;
      }
      sum += __shfl_xor(sum, 1);
      sum += __shfl_xor(sum, 2);
      sum += __shfl_xor(sum, 4);
      sum += __shfl_xor(sum, 8);
      l_r[r] = l_r[r] * alpha[r] + sum;
    }
#pragma unroll
    for (int dt = 0; dt < 4; dt++)
#pragma unroll
      for (int r = 0; r < 4; r++) o[dt][r] *= alpha[r];

    // P (C-layout) -> LDS -> A-operand layout (verified m120 transform)
    u16* P = &Psm[wave][0];
#pragma unroll
    for (int n = 0; n < 4; n++) {
      int kv = n * 16 + l16;
      int ccb = kv >> 3, ke = kv & 7;
#pragma unroll
      for (int r = 0; r < 4; r++) {
        int qr = quad * 4 + r;
        P[qr * 64 + ((ccb ^ (qr & 7)) * 8) + ke] = f2bf(S[n][r]);
      }
    }
    __syncthreads();

    bf16x8 pf[2];
#pragma unroll
    for (int ks = 0; ks < 2; ks++)
      pf[ks] = *(const bf16x8*)(P + l16 * 64 + (((ks * 4 + quad) ^ (l16 & 7)) * 8));
#pragma unroll
    for (int dt = 0; dt < 4; dt++) {
      int rv = dt * 16 + l16;
#pragma unroll
      for (int ks = 0; ks < 2; ks++) {
        bf16x8 vf =
            *(const bf16x8*)(Vsm + rv * 64 + (((ks * 4 + quad) ^ (rv & 7)) * 8));
        o[dt] = __builtin_amdgcn_mfma_f32_16x16x32_bf16(pf[ks], vf, o[dt], 0, 0, 0);
      }
    }
    __syncthreads();
  }

#pragma unroll
  for (int r = 0; r < 4; r++) {
    float inv = 1.f / l_r[r];
    int grow = b * T_ + qt * 64 + wave * 16 + quad * 4 + r;
#pragma unroll
    for (int dt = 0; dt < 4; dt++)
      y[(size_t)grow * C_ + h * 64 + dt * 16 + l16] = f2bf(o[dt][r] * inv);
  }
}

extern "C" void kernel_launch(void* const* d_in, const int* in_sizes, int n_in,
                              void* d_out, int out_size, void* d_ws, size_t ws_size,
                              hipStream_t stream) {
  const float* x  = (const float*)d_in[0];
  const float* wq = (const float*)d_in[1];
  const float* bq = (const float*)d_in[2];
  const float* wk = (const float*)d_in[3];
  const float* bk = (const float*)d_in[4];
  const float* wv = (const float*)d_in[5];
  const float* bv = (const float*)d_in[6];
  const float* wo = (const float*)d_in[7];
  const float* bo = (const float*)d_in[8];
  float* out = (float*)d_out;

  // workspace layout (bf16 elements), total ~92 MB
  u16* xb  = (u16*)d_ws;                    // [8192,1024]
  u16* wqb = xb  + (size_t)M_ * C_;         // [1024,1024]
  u16* wkb = wqb + (size_t)C_ * C_;
  u16* wvb = wkb + (size_t)C_ * C_;
  u16* wob = wvb + (size_t)C_ * C_;
  u16* qb  = wob + (size_t)C_ * C_;         // [8192,1024]
  u16* kb  = qb  + (size_t)M_ * C_;
  u16* vb  = kb  + (size_t)M_ * C_;
  u16* vtb = vb  + (size_t)M_ * C_;         // [(b*H+h)*64+d][2048]
  u16* yb  = xb;  // xb dead after QKV projections -> reuse for attention out

  cvt_bf16<<<(M_ * C_ / 4 + 255) / 256, 256, 0, stream>>>(x, xb, M_ * C_ / 4);
  cvt_bf16<<<(C_ * C_ / 4 + 255) / 256, 256, 0, stream>>>(wq, wqb, C_ * C_ / 4);
  cvt_bf16<<<(C_ * C_ / 4 + 255) / 256, 256, 0, stream>>>(wk, wkb, C_ * C_ / 4);
  cvt_bf16<<<(C_ * C_ / 4 + 255) / 256, 256, 0, stream>>>(wv, wvb, C_ * C_ / 4);
  cvt_bf16<<<(C_ * C_ / 4 + 255) / 256, 256, 0, stream>>>(wo, wob, C_ * C_ / 4);

  dim3 gg(C_ / 128, M_ / 128);  // (8, 64)
  gemm_bt<<<gg, 256, 0, stream>>>(xb, wqb, bq, nullptr, qb, M_, C_, C_);
  gemm_bt<<<gg, 256, 0, stream>>>(xb, wkb, bk, nullptr, kb, M_, C_, C_);
  gemm_bt<<<gg, 256, 0, stream>>>(xb, wvb, bv, nullptr, vb, M_, C_, C_);

  transpose_v<<<dim3(T_ / 64, B_ * H_), 256, 0, stream>>>(vb, vtb);
  attn<<<dim3(T_ / 64, B_ * H_), 256, 0, stream>>>(qb, kb, vtb, yb);

  gemm_bt<<<gg, 256, 0, stream>>>(yb, wob, bo, out, nullptr, M_, C_, C_);
}